// Round 5
// baseline (491.698 us; speedup 1.0000x reference)
//
#include <hip/hip_runtime.h>
#include <hip/hip_bf16.h>

#define NB 4
#define NH 16
#define NS 2048
#define ND 64
#define QBLK 128
#define KVBLK 64
#define NT (NS / KVBLK)
#define VSTRIDE 144   // bytes; odd multiple of 16 -> bank-even b128 reads
#define PSTRIDE 144
#define NEG_MIN -3.4028234663852886e38f
#define LOG2E 1.44269504088896340736f

typedef __attribute__((ext_vector_type(4))) float f32x4;
typedef __attribute__((ext_vector_type(8))) short bf16x8;
typedef __attribute__((ext_vector_type(4))) __bf16 bf16v4;
typedef __attribute__((ext_vector_type(8))) __bf16 bf16v8;

// ---- async staging, straight-line (NO lambdas: keeps kA..vD in VGPRs) ----
// K: thread covers rows krow+{0,16,32,48}, 4 floats at col kc4*4.
// V: lane owns column d=dl, k-quads at wid*4 + {0,16,32,48}.
#define ISSUE_LOADS(kv)                                                        \
    do {                                                                       \
        const float* kp = Kg + bh_base + (long)((kv) + krow) * ND + kc4 * 4;   \
        kA = *(const f32x4*)(kp);                                              \
        kB = *(const f32x4*)(kp + 16 * ND);                                    \
        kC = *(const f32x4*)(kp + 32 * ND);                                    \
        kD = *(const f32x4*)(kp + 48 * ND);                                    \
        const float* vp = vcol + (long)((kv) + wid * 4) * ND;                  \
        vA[0] = vp[0 * ND];  vA[1] = vp[1 * ND];                               \
        vA[2] = vp[2 * ND];  vA[3] = vp[3 * ND];                               \
        vB[0] = vp[16 * ND]; vB[1] = vp[17 * ND];                              \
        vB[2] = vp[18 * ND]; vB[3] = vp[19 * ND];                              \
        vC[0] = vp[32 * ND]; vC[1] = vp[33 * ND];                              \
        vC[2] = vp[34 * ND]; vC[3] = vp[35 * ND];                              \
        vD[0] = vp[48 * ND]; vD[1] = vp[49 * ND];                              \
        vD[2] = vp[50 * ND]; vD[3] = vp[51 * ND];                              \
        breg = (tid < KVBLK) ? Mg[(long)b * NS + (kv) + tid] : 1.0f;           \
    } while (0)

#define CVT4(dst, src)                                                         \
    do { dst[0] = (__bf16)src[0]; dst[1] = (__bf16)src[1];                     \
         dst[2] = (__bf16)src[2]; dst[3] = (__bf16)src[3]; } while (0)

// V store offsets are k_index*2 bytes, k_index = wid*4 + {0,16,32,48}
// (round-4 bug: these were doubled to {0,32,64,96} -> OOB past VSTRIDE -> NaN)
#define WRITE_LDS()                                                            \
    do {                                                                       \
        bf16v4 h;                                                              \
        int row = krow;                                                        \
        CVT4(h, kA);                                                           \
        *(bf16v4*)(Kl + ((row * 128 + kc4 * 8) ^ ((row & 7) << 4))) = h;       \
        row = krow + 16; CVT4(h, kB);                                          \
        *(bf16v4*)(Kl + ((row * 128 + kc4 * 8) ^ ((row & 7) << 4))) = h;       \
        row = krow + 32; CVT4(h, kC);                                          \
        *(bf16v4*)(Kl + ((row * 128 + kc4 * 8) ^ ((row & 7) << 4))) = h;       \
        row = krow + 48; CVT4(h, kD);                                          \
        *(bf16v4*)(Kl + ((row * 128 + kc4 * 8) ^ ((row & 7) << 4))) = h;       \
        CVT4(h, vA); *(bf16v4*)(Vl + dl * VSTRIDE + (wid * 4 +  0) * 2) = h;   \
        CVT4(h, vB); *(bf16v4*)(Vl + dl * VSTRIDE + (wid * 4 + 16) * 2) = h;   \
        CVT4(h, vC); *(bf16v4*)(Vl + dl * VSTRIDE + (wid * 4 + 32) * 2) = h;   \
        CVT4(h, vD); *(bf16v4*)(Vl + dl * VSTRIDE + (wid * 4 + 48) * 2) = h;   \
        if (tid < KVBLK) biasl[tid] = (1.0f - breg) * NEG_MIN * LOG2E;         \
    } while (0)

__global__ __launch_bounds__(256)
__attribute__((amdgpu_waves_per_eu(4, 4)))
void sdpa_fwd_kernel(
    const float* __restrict__ Qg, const float* __restrict__ Kg,
    const float* __restrict__ Vg, const float* __restrict__ Mg,
    float* __restrict__ Og)
{
    const int tid  = threadIdx.x;
    const int lane = tid & 63;
    const int wid  = tid >> 6;      // wave 0..3
    const int g    = lane >> 4;     // 0..3
    const int c    = lane & 15;     // 0..15

    // XCD-aware swizzle (bijective: 1024 % 8 == 0): XCD k owns heads [k*8, k*8+8)
    const int flat = (int)(blockIdx.x + blockIdx.y * gridDim.x);
    const int nf   = (flat & 7) * 128 + (flat >> 3);
    const int qt   = nf & 15;       // q tile (128 rows)
    const int bh   = nf >> 4;       // fused batch*head
    const int b    = bh >> 4;

    __shared__ char Kl[KVBLK * 128];          // 8 KB, bf16 row-major, XOR-swizzled
    __shared__ char Vl[ND * VSTRIDE];         // 9216 B, V^T [d][k] bf16
    __shared__ char Pl_all[4 * 32 * PSTRIDE]; // 18432 B, per-wave P
    __shared__ float biasl[KVBLK];
    char* Pw = Pl_all + wid * (32 * PSTRIDE);

    const long bh_base = (long)bh * NS * ND;

    // ---- Q fragments (B-operand: lane&15 = q, elems = k-dim), scale folded ----
    const float QSCALE = 0.125f * LOG2E;
    bf16x8 qfrag[2][2];
    #pragma unroll
    for (int s = 0; s < 2; ++s) {
        const float* qp = Qg + bh_base + (long)(qt * QBLK + wid * 32 + s * 16 + c) * ND;
        #pragma unroll
        for (int kk = 0; kk < 2; ++kk) {
            f32x4 f0 = *(const f32x4*)(qp + kk * 32 + g * 8);
            f32x4 f1 = *(const f32x4*)(qp + kk * 32 + g * 8 + 4);
            bf16v8 q;
            q[0] = (__bf16)(f0[0] * QSCALE); q[1] = (__bf16)(f0[1] * QSCALE);
            q[2] = (__bf16)(f0[2] * QSCALE); q[3] = (__bf16)(f0[3] * QSCALE);
            q[4] = (__bf16)(f1[0] * QSCALE); q[5] = (__bf16)(f1[1] * QSCALE);
            q[6] = (__bf16)(f1[2] * QSCALE); q[7] = (__bf16)(f1[3] * QSCALE);
            qfrag[s][kk] = *(bf16x8*)&q;
        }
    }

    float mrow[2] = {-1e30f, -1e30f};
    float lrow[2] = {0.0f, 0.0f};
    f32x4 oacc[2][4];
    #pragma unroll
    for (int s = 0; s < 2; ++s)
        #pragma unroll
        for (int dt = 0; dt < 4; ++dt) oacc[s][dt] = (f32x4){0.f, 0.f, 0.f, 0.f};

    // staging geometry
    const int krow = tid >> 4, kc4 = tid & 15;   // K: rows krow+16i, 4 floats each
    const int dl   = lane;                        // V: lane owns column d=dl
    const float* vcol = Vg + bh_base + dl;
    f32x4 kA, kB, kC, kD;                         // in-flight K tile (16 VGPR)
    f32x4 vA, vB, vC, vD;                         // in-flight V quads (16 VGPR)
    float breg;

    ISSUE_LOADS(0);
    WRITE_LDS();

    for (int it = 0; it < NT; ++it) {
        __syncthreads();                          // LDS tile `it` visible
        if (it + 1 < NT) {
            ISSUE_LOADS((it + 1) * KVBLK);        // in flight across compute
            __builtin_amdgcn_sched_barrier(0);    // pin load issue before compute
        }

        // ---- S^T = K Q^T : lane holds S[key=t*16+g*4+r][q=c] ----
        f32x4 st[2][4];
        #pragma unroll
        for (int t = 0; t < 4; ++t) {
            int key = t * 16 + c;
            int sw = (key & 7) << 4;
            bf16x8 kb0 = *(const bf16x8*)(Kl + ((key * 128 + g * 16) ^ sw));
            bf16x8 kb1 = *(const bf16x8*)(Kl + ((key * 128 + 64 + g * 16) ^ sw));
            f32x4 bias4 = *(const f32x4*)(biasl + t * 16 + g * 4);
            #pragma unroll
            for (int s = 0; s < 2; ++s) {
                f32x4 acc = (f32x4){0.f, 0.f, 0.f, 0.f};
                acc = __builtin_amdgcn_mfma_f32_16x16x32_bf16(kb0, qfrag[s][0], acc, 0, 0, 0);
                acc = __builtin_amdgcn_mfma_f32_16x16x32_bf16(kb1, qfrag[s][1], acc, 0, 0, 0);
                st[s][t] = acc + bias4;
            }
        }

        // ---- online softmax with defer-max (THR=8) ----
        #pragma unroll
        for (int s = 0; s < 2; ++s) {
            float tm = st[s][0][0];
            #pragma unroll
            for (int t = 0; t < 4; ++t)
                #pragma unroll
                for (int r = 0; r < 4; ++r) tm = fmaxf(tm, st[s][t][r]);
            tm = fmaxf(tm, __shfl_xor(tm, 16));
            tm = fmaxf(tm, __shfl_xor(tm, 32));
            if (!__all(tm <= mrow[s] + 8.0f)) {   // rare: max grew, rescale O
                float mnew = fmaxf(mrow[s], tm);
                float scl = __builtin_amdgcn_exp2f(mrow[s] - mnew);
                mrow[s] = mnew;
                lrow[s] *= scl;
                #pragma unroll
                for (int r = 0; r < 4; ++r) {
                    float sb = __shfl(scl, g * 4 + r);
                    #pragma unroll
                    for (int dt = 0; dt < 4; ++dt) oacc[s][dt][r] *= sb;
                }
            }
            float ps = 0.f;
            #pragma unroll
            for (int t = 0; t < 4; ++t) {
                bf16v4 pb;
                #pragma unroll
                for (int r = 0; r < 4; ++r) {
                    float p = __builtin_amdgcn_exp2f(st[s][t][r] - mrow[s]);
                    ps += p;
                    pb[r] = (__bf16)p;
                }
                *(bf16v4*)(Pw + (s * 16 + c) * PSTRIDE + (t * 16 + g * 4) * 2) = pb;
            }
            ps += __shfl_xor(ps, 16);
            ps += __shfl_xor(ps, 32);
            lrow[s] += ps;
        }

        // wave-internal LDS write->read fence (P is per-wave)
        asm volatile("s_waitcnt lgkmcnt(0)" ::: "memory");
        __builtin_amdgcn_sched_barrier(0);

        // ---- O += P V ----
        bf16x8 pa[2][2];
        #pragma unroll
        for (int s = 0; s < 2; ++s)
            #pragma unroll
            for (int h = 0; h < 2; ++h)
                pa[s][h] = *(const bf16x8*)(Pw + (s * 16 + c) * PSTRIDE + h * 64 + g * 16);
        #pragma unroll
        for (int dt = 0; dt < 4; ++dt) {
            int d = dt * 16 + c;
            bf16x8 vb0 = *(const bf16x8*)(Vl + d * VSTRIDE + g * 16);
            bf16x8 vb1 = *(const bf16x8*)(Vl + d * VSTRIDE + 64 + g * 16);
            #pragma unroll
            for (int s = 0; s < 2; ++s) {
                oacc[s][dt] = __builtin_amdgcn_mfma_f32_16x16x32_bf16(pa[s][0], vb0, oacc[s][dt], 0, 0, 0);
                oacc[s][dt] = __builtin_amdgcn_mfma_f32_16x16x32_bf16(pa[s][1], vb1, oacc[s][dt], 0, 0, 0);
            }
        }

        __syncthreads();                          // all waves done reading LDS
        if (it + 1 < NT) WRITE_LDS();             // stage tile it+1 (regs -> LDS)
    }

    // ---- epilogue: normalize and store ----
    #pragma unroll
    for (int s = 0; s < 2; ++s) {
        float inv = 1.0f / lrow[s];
        #pragma unroll
        for (int r = 0; r < 4; ++r) {
            float ib = __shfl(inv, g * 4 + r);
            float* op = Og + bh_base + (long)(qt * QBLK + wid * 32 + s * 16 + g * 4 + r) * ND;
            #pragma unroll
            for (int dt = 0; dt < 4; ++dt)
                op[dt * 16 + c] = oacc[s][dt][r] * ib;
        }
    }
}

extern "C" void kernel_launch(void* const* d_in, const int* in_sizes, int n_in,
                              void* d_out, int out_size, void* d_ws, size_t ws_size,
                              hipStream_t stream) {
    const float* Q = (const float*)d_in[0];
    const float* K = (const float*)d_in[1];
    const float* V = (const float*)d_in[2];
    const float* M = (const float*)d_in[3];
    float* O = (float*)d_out;

    dim3 grid(NS / QBLK, NB * NH);   // 16 x 64 = 1024 blocks
    dim3 block(256);
    sdpa_fwd_kernel<<<grid, block, 0, stream>>>(Q, K, V, M, O);
}

// Round 6
// 148.139 us; speedup vs baseline: 3.3192x; 3.3192x over previous
//
#include <hip/hip_runtime.h>
#include <hip/hip_bf16.h>

#define NB 4
#define NH 16
#define NS 2048
#define ND 64
#define QBLK 128
#define KVBLK 64
#define NT (NS / KVBLK)
#define PSTRIDE 144
#define NEG_MIN -3.4028234663852886e38f
#define LOG2E 1.44269504088896340736f
#define TILE_BYTES 8192
#define KWS_BYTES (64ull * 32ull * 8192ull)   // 16 MB

typedef __attribute__((ext_vector_type(4))) float f32x4;
typedef __attribute__((ext_vector_type(8))) short bf16x8;
typedef __attribute__((ext_vector_type(4))) __bf16 bf16v4;
typedef __attribute__((ext_vector_type(8))) __bf16 bf16v8;

#define GLL16(gp, lp) __builtin_amdgcn_global_load_lds(                        \
    (const __attribute__((address_space(1))) unsigned int*)(gp),              \
    (__attribute__((address_space(3))) unsigned int*)(lp), 16, 0, 0)
#define GLL4(gp, lp) __builtin_amdgcn_global_load_lds(                         \
    (const __attribute__((address_space(1))) unsigned int*)(gp),              \
    (__attribute__((address_space(3))) unsigned int*)(lp), 4, 0, 0)

// ---------------------------------------------------------------------------
// Pre-pass: K, V (fp32, [bh][k][d]) -> bf16 pre-swizzled 8KB tile images.
//  Kws tile: K[row][d]  at byte (row*128 + d*2) ^ ((row&7)<<4)
//  Vws tile: V^T[d][k]  at byte (d*128  + k*2) ^ ((d&7)<<4)
// ---------------------------------------------------------------------------
__global__ __launch_bounds__(256) void cvt_kv_kernel(
    const float* __restrict__ Kg, const float* __restrict__ Vg,
    char* __restrict__ Kws, char* __restrict__ Vws)
{
    const int tile = blockIdx.x;    // 0..31
    const int bh   = blockIdx.y;    // 0..63
    const int tid  = threadIdx.x;

    __shared__ float Vl[64][65];

    const long base = (long)bh * NS * ND + (long)tile * KVBLK * ND;
    char* kdst = Kws + ((long)bh * 32 + tile) * TILE_BYTES;
    char* vdst = Vws + ((long)bh * 32 + tile) * TILE_BYTES;

    #pragma unroll
    for (int i = 0; i < 4; ++i) {
        int v4 = tid + i * 256;         // 1024 vec4 chunks
        int row = v4 >> 4, c4 = v4 & 15;
        f32x4 f = *(const f32x4*)(Kg + base + row * ND + c4 * 4);
        bf16v4 h;
        h[0] = (__bf16)f[0]; h[1] = (__bf16)f[1];
        h[2] = (__bf16)f[2]; h[3] = (__bf16)f[3];
        *(bf16v4*)(kdst + ((row * 128 + c4 * 8) ^ ((row & 7) << 4))) = h;

        f32x4 v = *(const f32x4*)(Vg + base + row * ND + c4 * 4);
        Vl[row][c4 * 4 + 0] = v[0];
        Vl[row][c4 * 4 + 1] = v[1];
        Vl[row][c4 * 4 + 2] = v[2];
        Vl[row][c4 * 4 + 3] = v[3];
    }
    __syncthreads();
    #pragma unroll
    for (int i = 0; i < 4; ++i) {
        int v4 = tid + i * 256;
        int d = v4 >> 4, k4 = v4 & 15;
        bf16v4 h;
        h[0] = (__bf16)Vl[k4 * 4 + 0][d];
        h[1] = (__bf16)Vl[k4 * 4 + 1][d];
        h[2] = (__bf16)Vl[k4 * 4 + 2][d];
        h[3] = (__bf16)Vl[k4 * 4 + 3][d];
        *(bf16v4*)(vdst + ((d * 128 + k4 * 8) ^ ((d & 7) << 4))) = h;
    }
}

// mask -> log2-domain additive bias row, Bws[b][s]
__global__ __launch_bounds__(256) void bias_kernel(
    const float* __restrict__ Mg, float* __restrict__ Bws)
{
    int i = blockIdx.x * 256 + threadIdx.x;     // NB*NS = 8192
    float mv = Mg[i];
    Bws[i] = ((1.0f - mv) * NEG_MIN) * LOG2E;
}

// ---------------------------------------------------------------------------
// Main flash-attention kernel: bf16 tiles staged by global_load_lds,
// double-buffered LDS, counted vmcnt, raw barriers.
// ---------------------------------------------------------------------------
__global__ __launch_bounds__(256) void sdpa_fwd_kernel(
    const float* __restrict__ Qg, const char* __restrict__ Kws,
    const char* __restrict__ Vws, const float* __restrict__ Bws,
    float* __restrict__ Og)
{
    const int tid  = threadIdx.x;
    const int lane = tid & 63;
    const int wid  = tid >> 6;      // wave 0..3
    const int g    = lane >> 4;     // 0..3
    const int c    = lane & 15;     // 0..15

    // XCD-aware swizzle (bijective: 1024 % 8 == 0): XCD x owns heads [x*8, x*8+8)
    const int flat = (int)(blockIdx.x + blockIdx.y * gridDim.x);
    const int nf   = (flat & 7) * 128 + (flat >> 3);
    const int qt   = nf & 15;       // q tile (128 rows)
    const int bh   = nf >> 4;       // fused batch*head
    const int b    = bh >> 4;

    __shared__ char Kbuf[2][TILE_BYTES];       // 16 KB
    __shared__ char Vbuf[2][TILE_BYTES];       // 16 KB
    __shared__ float biasb[2][KVBLK];          // 512 B
    __shared__ char Pl_all[4 * 32 * PSTRIDE];  // 18 KB, per-wave P
    char* Pw = Pl_all + wid * (32 * PSTRIDE);

    const long bh_base = (long)bh * NS * ND;
    const char* ksrc = Kws + (long)bh * 32 * TILE_BYTES;
    const char* vsrc = Vws + (long)bh * 32 * TILE_BYTES;
    const char* bsrc = (const char*)(Bws + (long)b * NS);

#define STAGE(nt, bi)                                                          \
    do {                                                                       \
        const char* ks = ksrc + (nt) * TILE_BYTES;                             \
        const char* vs = vsrc + (nt) * TILE_BYTES;                             \
        int off = wid * 2048 + lane * 16;                                      \
        GLL16(ks + off,        &Kbuf[bi][off]);                                \
        GLL16(ks + off + 1024, &Kbuf[bi][off + 1024]);                         \
        GLL16(vs + off,        &Vbuf[bi][off]);                                \
        GLL16(vs + off + 1024, &Vbuf[bi][off + 1024]);                         \
        GLL4(bsrc + (nt) * 256 + lane * 4, (char*)&biasb[bi][0] + lane * 4);   \
    } while (0)

    STAGE(0, 0);    // tile 0 in flight; Q fragment prep hides its latency

    // ---- Q fragments (B-operand: lane&15 = q, elems = k-dim), scale folded --
    const float QSCALE = 0.125f * LOG2E;
    bf16x8 qfrag[2][2];
    #pragma unroll
    for (int s = 0; s < 2; ++s) {
        const float* qp = Qg + bh_base + (long)(qt * QBLK + wid * 32 + s * 16 + c) * ND;
        #pragma unroll
        for (int kk = 0; kk < 2; ++kk) {
            f32x4 f0 = *(const f32x4*)(qp + kk * 32 + g * 8);
            f32x4 f1 = *(const f32x4*)(qp + kk * 32 + g * 8 + 4);
            bf16v8 q;
            q[0] = (__bf16)(f0[0] * QSCALE); q[1] = (__bf16)(f0[1] * QSCALE);
            q[2] = (__bf16)(f0[2] * QSCALE); q[3] = (__bf16)(f0[3] * QSCALE);
            q[4] = (__bf16)(f1[0] * QSCALE); q[5] = (__bf16)(f1[1] * QSCALE);
            q[6] = (__bf16)(f1[2] * QSCALE); q[7] = (__bf16)(f1[3] * QSCALE);
            qfrag[s][kk] = *(bf16x8*)&q;
        }
    }

    float mrow[2] = {-1e30f, -1e30f};
    float lrow[2] = {0.0f, 0.0f};
    f32x4 oacc[2][4];
    #pragma unroll
    for (int s = 0; s < 2; ++s)
        #pragma unroll
        for (int dt = 0; dt < 4; ++dt) oacc[s][dt] = (f32x4){0.f, 0.f, 0.f, 0.f};

    for (int it = 0; it < NT; ++it) {
        const int bi = it & 1;
        if (it + 1 < NT) {
            STAGE(it + 1, bi ^ 1);                    // next tile: in flight
            asm volatile("s_waitcnt vmcnt(5)" ::: "memory");  // tile it done
        } else {
            asm volatile("s_waitcnt vmcnt(0)" ::: "memory");
        }
        __builtin_amdgcn_s_barrier();
        __builtin_amdgcn_sched_barrier(0);

        // ---- S^T = K Q^T : lane holds S[key=t*16+g*4+r][q=c] ----
        f32x4 st[2][4];
        #pragma unroll
        for (int t = 0; t < 4; ++t) {
            int key = t * 16 + c;
            int sw = (key & 7) << 4;
            bf16x8 kb0 = *(const bf16x8*)(&Kbuf[bi][0] + ((key * 128 + g * 16) ^ sw));
            bf16x8 kb1 = *(const bf16x8*)(&Kbuf[bi][0] + ((key * 128 + 64 + g * 16) ^ sw));
            f32x4 bias4 = *(const f32x4*)(&biasb[bi][t * 16 + g * 4]);
            #pragma unroll
            for (int s = 0; s < 2; ++s) {
                f32x4 acc = (f32x4){0.f, 0.f, 0.f, 0.f};
                acc = __builtin_amdgcn_mfma_f32_16x16x32_bf16(kb0, qfrag[s][0], acc, 0, 0, 0);
                acc = __builtin_amdgcn_mfma_f32_16x16x32_bf16(kb1, qfrag[s][1], acc, 0, 0, 0);
                st[s][t] = acc + bias4;
            }
        }

        // ---- online softmax with defer-max (THR=8) ----
        #pragma unroll
        for (int s = 0; s < 2; ++s) {
            float tm = st[s][0][0];
            #pragma unroll
            for (int t = 0; t < 4; ++t)
                #pragma unroll
                for (int r = 0; r < 4; ++r) tm = fmaxf(tm, st[s][t][r]);
            tm = fmaxf(tm, __shfl_xor(tm, 16));
            tm = fmaxf(tm, __shfl_xor(tm, 32));
            if (!__all(tm <= mrow[s] + 8.0f)) {   // rare: max grew, rescale O
                float mnew = fmaxf(mrow[s], tm);
                float scl = __builtin_amdgcn_exp2f(mrow[s] - mnew);
                mrow[s] = mnew;
                lrow[s] *= scl;
                #pragma unroll
                for (int r = 0; r < 4; ++r) {
                    float sb = __shfl(scl, g * 4 + r);
                    #pragma unroll
                    for (int dt = 0; dt < 4; ++dt) oacc[s][dt][r] *= sb;
                }
            }
            float ps = 0.f;
            #pragma unroll
            for (int t = 0; t < 4; ++t) {
                bf16v4 pb;
                #pragma unroll
                for (int r = 0; r < 4; ++r) {
                    float p = __builtin_amdgcn_exp2f(st[s][t][r] - mrow[s]);
                    ps += p;
                    pb[r] = (__bf16)p;
                }
                *(bf16v4*)(Pw + (s * 16 + c) * PSTRIDE + (t * 16 + g * 4) * 2) = pb;
            }
            ps += __shfl_xor(ps, 16);
            ps += __shfl_xor(ps, 32);
            lrow[s] += ps;
        }

        // wave-internal LDS write->read fence (P is per-wave)
        asm volatile("s_waitcnt lgkmcnt(0)" ::: "memory");
        __builtin_amdgcn_sched_barrier(0);

        // ---- O += P V ----
        bf16x8 pa[2][2];
        #pragma unroll
        for (int s = 0; s < 2; ++s)
            #pragma unroll
            for (int h = 0; h < 2; ++h)
                pa[s][h] = *(const bf16x8*)(Pw + (s * 16 + c) * PSTRIDE + h * 64 + g * 16);
        #pragma unroll
        for (int dt = 0; dt < 4; ++dt) {
            int d = dt * 16 + c;
            int swv = (d & 7) << 4;
            bf16x8 vb0 = *(const bf16x8*)(&Vbuf[bi][0] + ((d * 128 + g * 16) ^ swv));
            bf16x8 vb1 = *(const bf16x8*)(&Vbuf[bi][0] + ((d * 128 + 64 + g * 16) ^ swv));
            #pragma unroll
            for (int s = 0; s < 2; ++s) {
                oacc[s][dt] = __builtin_amdgcn_mfma_f32_16x16x32_bf16(pa[s][0], vb0, oacc[s][dt], 0, 0, 0);
                oacc[s][dt] = __builtin_amdgcn_mfma_f32_16x16x32_bf16(pa[s][1], vb1, oacc[s][dt], 0, 0, 0);
            }
        }

        // all waves done reading buf bi before it is re-staged at iter it+1
        asm volatile("" ::: "memory");
        __builtin_amdgcn_s_barrier();
        __builtin_amdgcn_sched_barrier(0);
    }
#undef STAGE

    // ---- epilogue: normalize and store ----
    #pragma unroll
    for (int s = 0; s < 2; ++s) {
        float inv = 1.0f / lrow[s];
        #pragma unroll
        for (int r = 0; r < 4; ++r) {
            float ib = __shfl(inv, g * 4 + r);
            float* op = Og + bh_base + (long)(qt * QBLK + wid * 32 + s * 16 + g * 4 + r) * ND;
            #pragma unroll
            for (int dt = 0; dt < 4; ++dt)
                op[dt * 16 + c] = oacc[s][dt][r] * ib;
        }
    }
}

// ---------------------------------------------------------------------------
// Fallback (round-2 verified kernel, 286 us) if ws_size is too small.
// ---------------------------------------------------------------------------
#define VSTRIDE_FB 144
__global__ __launch_bounds__(256, 4) void sdpa_fb_kernel(
    const float* __restrict__ Qg, const float* __restrict__ Kg,
    const float* __restrict__ Vg, const float* __restrict__ Mg,
    float* __restrict__ Og)
{
    const int tid  = threadIdx.x;
    const int lane = tid & 63;
    const int wid  = tid >> 6;
    const int g    = lane >> 4;
    const int c    = lane & 15;

    const int qt = blockIdx.x;
    const int bh = blockIdx.y;
    const int b  = bh >> 4;

    __shared__ char Kl[KVBLK * 128];
    __shared__ char Vl[ND * VSTRIDE_FB];
    __shared__ char Pl_all[4 * 32 * PSTRIDE];
    __shared__ float biasl[KVBLK];
    char* Pw = Pl_all + wid * (32 * PSTRIDE);

    const long bh_base = (long)bh * NS * ND;

    const float QSCALE = 0.125f * LOG2E;
    bf16x8 qfrag[2][2];
    #pragma unroll
    for (int s = 0; s < 2; ++s) {
        const float* qp = Qg + bh_base + (long)(qt * QBLK + wid * 32 + s * 16 + c) * ND;
        #pragma unroll
        for (int kk = 0; kk < 2; ++kk) {
            f32x4 f0 = *(const f32x4*)(qp + kk * 32 + g * 8);
            f32x4 f1 = *(const f32x4*)(qp + kk * 32 + g * 8 + 4);
            bf16v8 q;
            q[0] = (__bf16)(f0[0] * QSCALE); q[1] = (__bf16)(f0[1] * QSCALE);
            q[2] = (__bf16)(f0[2] * QSCALE); q[3] = (__bf16)(f0[3] * QSCALE);
            q[4] = (__bf16)(f1[0] * QSCALE); q[5] = (__bf16)(f1[1] * QSCALE);
            q[6] = (__bf16)(f1[2] * QSCALE); q[7] = (__bf16)(f1[3] * QSCALE);
            qfrag[s][kk] = *(bf16x8*)&q;
        }
    }

    float mrow[2] = {-1e30f, -1e30f};
    float lrow[2] = {0.0f, 0.0f};
    f32x4 oacc[2][4];
    #pragma unroll
    for (int s = 0; s < 2; ++s)
        #pragma unroll
        for (int dt = 0; dt < 4; ++dt) oacc[s][dt] = (f32x4){0.f, 0.f, 0.f, 0.f};

    const int dl = lane;
    const float* vcol = Vg + bh_base + dl;

    for (int kv0 = 0; kv0 < NS; kv0 += KVBLK) {
        #pragma unroll
        for (int i = 0; i < 4; ++i) {
            int cc = tid + i * 256;
            int row = cc >> 4, c4 = cc & 15;
            f32x4 f = *(const f32x4*)(Kg + bh_base + (long)(kv0 + row) * ND + c4 * 4);
            bf16v4 h;
            h[0] = (__bf16)f[0]; h[1] = (__bf16)f[1];
            h[2] = (__bf16)f[2]; h[3] = (__bf16)f[3];
            *(bf16v4*)(Kl + ((row * 128 + c4 * 8) ^ ((row & 7) << 4))) = h;
        }
        #pragma unroll
        for (int i = 0; i < 4; ++i) {
            int k0 = (wid + i * 4) * 4;
            float v0 = vcol[(long)(kv0 + k0 + 0) * ND];
            float v1 = vcol[(long)(kv0 + k0 + 1) * ND];
            float v2 = vcol[(long)(kv0 + k0 + 2) * ND];
            float v3 = vcol[(long)(kv0 + k0 + 3) * ND];
            bf16v4 h;
            h[0] = (__bf16)v0; h[1] = (__bf16)v1; h[2] = (__bf16)v2; h[3] = (__bf16)v3;
            *(bf16v4*)(Vl + dl * VSTRIDE_FB + k0 * 2) = h;
        }
        if (tid < KVBLK) {
            float mv = Mg[(long)b * NS + kv0 + tid];
            biasl[tid] = ((1.0f - mv) * NEG_MIN) * LOG2E;
        }
        __syncthreads();

        f32x4 st[2][4];
        #pragma unroll
        for (int t = 0; t < 4; ++t) {
            int key = t * 16 + c;
            int sw = (key & 7) << 4;
            bf16x8 kb0 = *(const bf16x8*)(Kl + ((key * 128 + g * 16) ^ sw));
            bf16x8 kb1 = *(const bf16x8*)(Kl + ((key * 128 + 64 + g * 16) ^ sw));
            f32x4 bias4 = *(const f32x4*)(biasl + t * 16 + g * 4);
            #pragma unroll
            for (int s = 0; s < 2; ++s) {
                f32x4 acc = (f32x4){0.f, 0.f, 0.f, 0.f};
                acc = __builtin_amdgcn_mfma_f32_16x16x32_bf16(kb0, qfrag[s][0], acc, 0, 0, 0);
                acc = __builtin_amdgcn_mfma_f32_16x16x32_bf16(kb1, qfrag[s][1], acc, 0, 0, 0);
                st[s][t] = acc + bias4;
            }
        }

        #pragma unroll
        for (int s = 0; s < 2; ++s) {
            float tm = st[s][0][0];
            #pragma unroll
            for (int t = 0; t < 4; ++t)
                #pragma unroll
                for (int r = 0; r < 4; ++r) tm = fmaxf(tm, st[s][t][r]);
            tm = fmaxf(tm, __shfl_xor(tm, 16));
            tm = fmaxf(tm, __shfl_xor(tm, 32));
            float mnew = fmaxf(mrow[s], tm);
            float scl = __builtin_amdgcn_exp2f(mrow[s] - mnew);
            mrow[s] = mnew;
            float ps = 0.f;
            #pragma unroll
            for (int t = 0; t < 4; ++t) {
                bf16v4 pb;
                #pragma unroll
                for (int r = 0; r < 4; ++r) {
                    float p = __builtin_amdgcn_exp2f(st[s][t][r] - mnew);
                    ps += p;
                    pb[r] = (__bf16)p;
                }
                *(bf16v4*)(Pw + (s * 16 + c) * PSTRIDE + (t * 16 + g * 4) * 2) = pb;
            }
            ps += __shfl_xor(ps, 16);
            ps += __shfl_xor(ps, 32);
            lrow[s] = lrow[s] * scl + ps;
            #pragma unroll
            for (int r = 0; r < 4; ++r) {
                float sb = __shfl(scl, g * 4 + r);
                #pragma unroll
                for (int dt = 0; dt < 4; ++dt) oacc[s][dt][r] *= sb;
            }
        }

        asm volatile("s_waitcnt lgkmcnt(0)" ::: "memory");
        __builtin_amdgcn_sched_barrier(0);

        bf16x8 pa[2][2];
        #pragma unroll
        for (int s = 0; s < 2; ++s)
            #pragma unroll
            for (int h = 0; h < 2; ++h)
                pa[s][h] = *(const bf16x8*)(Pw + (s * 16 + c) * PSTRIDE + h * 64 + g * 16);
        #pragma unroll
        for (int dt = 0; dt < 4; ++dt) {
            int d = dt * 16 + c;
            bf16x8 vb0 = *(const bf16x8*)(Vl + d * VSTRIDE_FB + g * 16);
            bf16x8 vb1 = *(const bf16x8*)(Vl + d * VSTRIDE_FB + 64 + g * 16);
            #pragma unroll
            for (int s = 0; s < 2; ++s) {
                oacc[s][dt] = __builtin_amdgcn_mfma_f32_16x16x32_bf16(pa[s][0], vb0, oacc[s][dt], 0, 0, 0);
                oacc[s][dt] = __builtin_amdgcn_mfma_f32_16x16x32_bf16(pa[s][1], vb1, oacc[s][dt], 0, 0, 0);
            }
        }
        __syncthreads();
    }

    #pragma unroll
    for (int s = 0; s < 2; ++s) {
        float inv = 1.0f / lrow[s];
        #pragma unroll
        for (int r = 0; r < 4; ++r) {
            float ib = __shfl(inv, g * 4 + r);
            float* op = Og + bh_base + (long)(qt * QBLK + wid * 32 + s * 16 + g * 4 + r) * ND;
            #pragma unroll
            for (int dt = 0; dt < 4; ++dt)
                op[dt * 16 + c] = oacc[s][dt][r] * ib;
        }
    }
}

extern "C" void kernel_launch(void* const* d_in, const int* in_sizes, int n_in,
                              void* d_out, int out_size, void* d_ws, size_t ws_size,
                              hipStream_t stream) {
    const float* Q = (const float*)d_in[0];
    const float* K = (const float*)d_in[1];
    const float* V = (const float*)d_in[2];
    const float* M = (const float*)d_in[3];
    float* O = (float*)d_out;

    const size_t need = 2 * KWS_BYTES + (size_t)NB * NS * sizeof(float);
    if (ws_size >= need) {
        char*  Kws = (char*)d_ws;
        char*  Vws = Kws + KWS_BYTES;
        float* Bws = (float*)(Kws + 2 * KWS_BYTES);
        cvt_kv_kernel<<<dim3(32, 64), 256, 0, stream>>>(K, V, Kws, Vws);
        bias_kernel<<<dim3(NB * NS / 256), 256, 0, stream>>>(M, Bws);
        sdpa_fwd_kernel<<<dim3(16, 64), 256, 0, stream>>>(Q, Kws, Vws, Bws, O);
    } else {
        sdpa_fb_kernel<<<dim3(16, 64), 256, 0, stream>>>(Q, K, V, M, O);
    }
}

// Round 7
// 137.196 us; speedup vs baseline: 3.5839x; 1.0798x over previous
//
#include <hip/hip_runtime.h>
#include <hip/hip_bf16.h>

#define NB 4
#define NH 16
#define NS 2048
#define ND 64
#define KVBLK 64
#define NT (NS / KVBLK)
#define PSTRIDE 144
#define NEG_MIN -3.4028234663852886e38f
#define LOG2E 1.44269504088896340736f
#define TILE_BYTES 8192
#define KWS_BYTES (64ull * 32ull * 8192ull)   // 16 MB

typedef __attribute__((ext_vector_type(4))) float f32x4;
typedef __attribute__((ext_vector_type(16))) float f32x16;
typedef __attribute__((ext_vector_type(8))) short bf16x8;
typedef __attribute__((ext_vector_type(4))) __bf16 bf16v4;
typedef __attribute__((ext_vector_type(8))) __bf16 bf16v8;
typedef __attribute__((ext_vector_type(4))) unsigned u32x4;

#define GLL16(gp, lp) __builtin_amdgcn_global_load_lds(                        \
    (const __attribute__((address_space(1))) unsigned int*)(gp),              \
    (__attribute__((address_space(3))) unsigned int*)(lp), 16, 0, 0)

__device__ __forceinline__ unsigned pk2(float lo, float hi) {
    union { __bf16 h[2]; unsigned u; } x;
    x.h[0] = (__bf16)lo; x.h[1] = (__bf16)hi;
    return x.u;
}

// ---------------------------------------------------------------------------
// Pre-pass: K, V (fp32, [bh][k][d]) -> bf16 pre-swizzled 8KB tile images.
//  Kws tile: K[row][d]  at byte (row*128 + d*2) ^ ((row&7)<<4)
//  Vws tile: V^T[d][k]  at byte (d*128  + k*2) ^ ((d&7)<<4)
// ---------------------------------------------------------------------------
__global__ __launch_bounds__(256) void cvt_kv_kernel(
    const float* __restrict__ Kg, const float* __restrict__ Vg,
    char* __restrict__ Kws, char* __restrict__ Vws)
{
    const int tile = blockIdx.x;    // 0..31
    const int bh   = blockIdx.y;    // 0..63
    const int tid  = threadIdx.x;

    __shared__ float Vl[64][65];

    const long base = (long)bh * NS * ND + (long)tile * KVBLK * ND;
    char* kdst = Kws + ((long)bh * 32 + tile) * TILE_BYTES;
    char* vdst = Vws + ((long)bh * 32 + tile) * TILE_BYTES;

    #pragma unroll
    for (int i = 0; i < 4; ++i) {
        int v4 = tid + i * 256;         // 1024 vec4 chunks
        int row = v4 >> 4, c4 = v4 & 15;
        f32x4 f = *(const f32x4*)(Kg + base + row * ND + c4 * 4);
        bf16v4 h;
        h[0] = (__bf16)f[0]; h[1] = (__bf16)f[1];
        h[2] = (__bf16)f[2]; h[3] = (__bf16)f[3];
        *(bf16v4*)(kdst + ((row * 128 + c4 * 8) ^ ((row & 7) << 4))) = h;

        f32x4 v = *(const f32x4*)(Vg + base + row * ND + c4 * 4);
        Vl[row][c4 * 4 + 0] = v[0];
        Vl[row][c4 * 4 + 1] = v[1];
        Vl[row][c4 * 4 + 2] = v[2];
        Vl[row][c4 * 4 + 3] = v[3];
    }
    __syncthreads();
    #pragma unroll
    for (int i = 0; i < 4; ++i) {
        int v4 = tid + i * 256;
        int d = v4 >> 4, k4 = v4 & 15;
        bf16v4 h;
        h[0] = (__bf16)Vl[k4 * 4 + 0][d];
        h[1] = (__bf16)Vl[k4 * 4 + 1][d];
        h[2] = (__bf16)Vl[k4 * 4 + 2][d];
        h[3] = (__bf16)Vl[k4 * 4 + 3][d];
        *(bf16v4*)(vdst + ((d * 128 + k4 * 8) ^ ((d & 7) << 4))) = h;
    }
}

// mask -> log2-domain additive bias row, Bws[b][s]
__global__ __launch_bounds__(256) void bias_kernel(
    const float* __restrict__ Mg, float* __restrict__ Bws)
{
    int i = blockIdx.x * 256 + threadIdx.x;     // NB*NS = 8192
    float mv = Mg[i];
    Bws[i] = ((1.0f - mv) * NEG_MIN) * LOG2E;
}

// ---------------------------------------------------------------------------
// Main: 8-wave 32x32 swapped-QK^T flash attention, softmax fully in-register.
//  - per wave: 32 q-rows; QBLK = 256; grid 8 x 64 = 512 blocks (2/CU exact)
//  - C-layout (m74/m101): col=lane&31, row=crow(r,hi)=(r&3)+8*(r>>2)+4*hi
//  - swapped QK^T (A=K,B=Q): lane q=lane&31 holds S[crow(r,hi)][q] in regs
//  - PV A-fragments built in-register: pack bf16 pairs + lane^32 exchange
// ---------------------------------------------------------------------------
__global__ __launch_bounds__(512, 4) void sdpa_fwd_kernel(
    const float* __restrict__ Qg, const char* __restrict__ Kws,
    const char* __restrict__ Vws, const float* __restrict__ Bws,
    float* __restrict__ Og)
{
    const int tid  = threadIdx.x;
    const int lane = tid & 63;
    const int wid  = tid >> 6;      // wave 0..7
    const int l31  = lane & 31;
    const int hi   = lane >> 5;     // 0/1

    // XCD-aware swizzle (bijective: 512 % 8 == 0): XCD x owns heads [x*8, x*8+8)
    const int flat = (int)(blockIdx.x + blockIdx.y * gridDim.x);
    const int nf   = (flat & 7) * 64 + (flat >> 3);
    const int qt   = nf & 7;        // q tile of 256 rows
    const int bh   = nf >> 3;       // fused batch*head
    const int b    = bh >> 4;

    __shared__ char Kbuf[2][TILE_BYTES];   // 16 KB
    __shared__ char Vbuf[2][TILE_BYTES];   // 16 KB
    __shared__ float biasrow[NS];          // 8 KB, whole bias row for batch b

    const long bh_base = (long)bh * NS * ND;
    const char* ksrc = Kws + (long)bh * NT * TILE_BYTES;
    const char* vsrc = Vws + (long)bh * NT * TILE_BYTES;

    // ---- prologue staging: bias row + tile 0 ----
    GLL16((const char*)(Bws + (long)b * NS) + tid * 16, ((char*)biasrow) + tid * 16);
    GLL16(ksrc + tid * 16, &Kbuf[0][tid * 16]);
    GLL16(vsrc + tid * 16, &Vbuf[0][tid * 16]);
    asm volatile("s_waitcnt vmcnt(0)" ::: "memory");
    __syncthreads();

    int any;
    {
        f32x4 bb = *(const f32x4*)&biasrow[tid * 4];
        any = (bb[0] != 0.f) | (bb[1] != 0.f) | (bb[2] != 0.f) | (bb[3] != 0.f);
    }
    const int has_bias = __syncthreads_or(any);

    // ---- Q fragments (B-operand: col=q=lane&31, k = hi*8+e per ks) ----
    const int q0 = qt * 256 + wid * 32;
    const float QSCALE = 0.125f * LOG2E;
    bf16x8 qfrag[4];
    {
        const float* qp = Qg + bh_base + (long)(q0 + l31) * ND;
        #pragma unroll
        for (int ks = 0; ks < 4; ++ks) {
            f32x4 fa = *(const f32x4*)(qp + ks * 16 + hi * 8);
            f32x4 fb = *(const f32x4*)(qp + ks * 16 + hi * 8 + 4);
            bf16v8 q;
            q[0] = (__bf16)(fa[0] * QSCALE); q[1] = (__bf16)(fa[1] * QSCALE);
            q[2] = (__bf16)(fa[2] * QSCALE); q[3] = (__bf16)(fa[3] * QSCALE);
            q[4] = (__bf16)(fb[0] * QSCALE); q[5] = (__bf16)(fb[1] * QSCALE);
            q[6] = (__bf16)(fb[2] * QSCALE); q[7] = (__bf16)(fb[3] * QSCALE);
            qfrag[ks] = *(bf16x8*)&q;
        }
    }

    float mrow = -1e30f, lrow = 0.0f;
    f32x16 oa, ob;                 // O accum: d = l31 (oa) / 32+l31 (ob), row=crow
    #pragma unroll
    for (int r = 0; r < 16; ++r) { oa[r] = 0.f; ob[r] = 0.f; }

    const int sw = (l31 & 7) << 4;     // XOR swizzle, same for rows l31 / 32+l31

    for (int t = 0; t < NT; ++t) {
        const int bi = t & 1;
        if (t + 1 < NT) {
            const char* ks_ = ksrc + (long)(t + 1) * TILE_BYTES;
            const char* vs_ = vsrc + (long)(t + 1) * TILE_BYTES;
            GLL16(ks_ + tid * 16, &Kbuf[bi ^ 1][tid * 16]);
            GLL16(vs_ + tid * 16, &Vbuf[bi ^ 1][tid * 16]);
            asm volatile("s_waitcnt vmcnt(2)" ::: "memory");   // tile t landed
        } else {
            asm volatile("s_waitcnt vmcnt(0)" ::: "memory");
        }
        __builtin_amdgcn_s_barrier();
        __builtin_amdgcn_sched_barrier(0);

        // ---- S^T = K Q^T : s0 keys kb=0 (0..31), s1 keys kb=1 (32..63) ----
        f32x16 s0, s1;
        #pragma unroll
        for (int r = 0; r < 16; ++r) { s0[r] = 0.f; s1[r] = 0.f; }
        #pragma unroll
        for (int ks = 0; ks < 4; ++ks) {
            bf16x8 kf0 = *(const bf16x8*)(&Kbuf[bi][0] + ((l31 * 128        + ks * 32 + hi * 16) ^ sw));
            bf16x8 kf1 = *(const bf16x8*)(&Kbuf[bi][0] + (((32 + l31) * 128 + ks * 32 + hi * 16) ^ sw));
            s0 = __builtin_amdgcn_mfma_f32_32x32x16_bf16(kf0, qfrag[ks], s0, 0, 0, 0);
            s1 = __builtin_amdgcn_mfma_f32_32x32x16_bf16(kf1, qfrag[ks], s1, 0, 0, 0);
        }

        if (has_bias) {
            #pragma unroll
            for (int q4 = 0; q4 < 4; ++q4) {
                f32x4 b0 = *(const f32x4*)&biasrow[t * 64      + q4 * 8 + hi * 4];
                f32x4 b1 = *(const f32x4*)&biasrow[t * 64 + 32 + q4 * 8 + hi * 4];
                #pragma unroll
                for (int j = 0; j < 4; ++j) {
                    s0[q4 * 4 + j] += b0[j];
                    s1[q4 * 4 + j] += b1[j];
                }
            }
        }

        // ---- in-register online softmax (row q = l31, replicated across hi) --
        float tm = s0[0];
        #pragma unroll
        for (int r = 1; r < 16; ++r) tm = fmaxf(tm, s0[r]);
        #pragma unroll
        for (int r = 0; r < 16; ++r) tm = fmaxf(tm, s1[r]);
        tm = fmaxf(tm, __shfl_xor(tm, 32));

        if (!__all(tm <= mrow + 8.0f)) {       // defer-max: rescale is rare
            float mnew = fmaxf(mrow, tm);
            float scl = __builtin_amdgcn_exp2f(mrow - mnew);
            mrow = mnew; lrow *= scl;
            #pragma unroll
            for (int r = 0; r < 16; ++r) {
                int qr = (r & 3) + 8 * (r >> 2) + 4 * hi;
                float sb = __shfl(scl, qr);
                oa[r] *= sb; ob[r] *= sb;
            }
        }

        float ps = 0.f;
        #pragma unroll
        for (int r = 0; r < 16; ++r) { s0[r] = __builtin_amdgcn_exp2f(s0[r] - mrow); ps += s0[r]; }
        #pragma unroll
        for (int r = 0; r < 16; ++r) { s1[r] = __builtin_amdgcn_exp2f(s1[r] - mrow); ps += s1[r]; }
        ps += __shfl_xor(ps, 32);
        lrow += ps;

        // ---- P -> bf16 PA fragments in-register, then O += P V ----
        // word w of PA(ks): source half (w>>1)&1, reg pair r=(2w&3)+8ks+4*hi_tgt
        #pragma unroll
        for (int kb = 0; kb < 2; ++kb) {
            const f32x16 p = kb ? s1 : s0;
            bf16x8 paf[2];
            #pragma unroll
            for (int ks = 0; ks < 2; ++ks) {
                unsigned A = pk2(p[8 * ks + 0], p[8 * ks + 1]);
                unsigned C = pk2(p[8 * ks + 2], p[8 * ks + 3]);
                unsigned B = pk2(p[8 * ks + 4], p[8 * ks + 5]);
                unsigned D = pk2(p[8 * ks + 6], p[8 * ks + 7]);
                unsigned Ax = __shfl_xor(A, 32);
                unsigned Bx = __shfl_xor(B, 32);
                unsigned Cx = __shfl_xor(C, 32);
                unsigned Dx = __shfl_xor(D, 32);
                u32x4 w;
                w[0] = hi ? Bx : A;
                w[1] = hi ? Dx : C;
                w[2] = hi ? B : Ax;
                w[3] = hi ? D : Cx;
                paf[ks] = *(bf16x8*)&w;
            }
            #pragma unroll
            for (int ks = 0; ks < 2; ++ks) {
                bf16x8 v0 = *(const bf16x8*)(&Vbuf[bi][0] + ((l31 * 128        + kb * 64 + ks * 32 + hi * 16) ^ sw));
                bf16x8 v1 = *(const bf16x8*)(&Vbuf[bi][0] + (((32 + l31) * 128 + kb * 64 + ks * 32 + hi * 16) ^ sw));
                oa = __builtin_amdgcn_mfma_f32_32x32x16_bf16(paf[ks], v0, oa, 0, 0, 0);
                ob = __builtin_amdgcn_mfma_f32_32x32x16_bf16(paf[ks], v1, ob, 0, 0, 0);
            }
        }

        __builtin_amdgcn_s_barrier();          // all waves done with buf bi
        __builtin_amdgcn_sched_barrier(0);
    }

    // ---- epilogue: normalize (1/l broadcast per crow) and store fp32 ----
    float inv = 1.0f / lrow;
    #pragma unroll
    for (int r = 0; r < 16; ++r) {
        int qr = (r & 3) + 8 * (r >> 2) + 4 * hi;
        float iv = __shfl(inv, qr);
        float* op = Og + bh_base + (long)(q0 + qr) * ND + l31;
        op[0]  = oa[r] * iv;
        op[32] = ob[r] * iv;
    }
}

// ---------------------------------------------------------------------------
// Fallback (round-2 verified kernel) if ws_size is too small.
// ---------------------------------------------------------------------------
#define VSTRIDE_FB 144
__global__ __launch_bounds__(256, 4) void sdpa_fb_kernel(
    const float* __restrict__ Qg, const float* __restrict__ Kg,
    const float* __restrict__ Vg, const float* __restrict__ Mg,
    float* __restrict__ Og)
{
    const int tid  = threadIdx.x;
    const int lane = tid & 63;
    const int wid  = tid >> 6;
    const int g    = lane >> 4;
    const int c    = lane & 15;

    const int qt = blockIdx.x;
    const int bh = blockIdx.y;
    const int b  = bh >> 4;

    __shared__ char Kl[KVBLK * 128];
    __shared__ char Vl[ND * VSTRIDE_FB];
    __shared__ char Pl_all[4 * 32 * PSTRIDE];
    __shared__ float biasl[KVBLK];
    char* Pw = Pl_all + wid * (32 * PSTRIDE);

    const long bh_base = (long)bh * NS * ND;

    const float QSCALE = 0.125f * LOG2E;
    bf16x8 qfrag[2][2];
    #pragma unroll
    for (int s = 0; s < 2; ++s) {
        const float* qp = Qg + bh_base + (long)(qt * 128 + wid * 32 + s * 16 + c) * ND;
        #pragma unroll
        for (int kk = 0; kk < 2; ++kk) {
            f32x4 f0 = *(const f32x4*)(qp + kk * 32 + g * 8);
            f32x4 f1 = *(const f32x4*)(qp + kk * 32 + g * 8 + 4);
            bf16v8 q;
            q[0] = (__bf16)(f0[0] * QSCALE); q[1] = (__bf16)(f0[1] * QSCALE);
            q[2] = (__bf16)(f0[2] * QSCALE); q[3] = (__bf16)(f0[3] * QSCALE);
            q[4] = (__bf16)(f1[0] * QSCALE); q[5] = (__bf16)(f1[1] * QSCALE);
            q[6] = (__bf16)(f1[2] * QSCALE); q[7] = (__bf16)(f1[3] * QSCALE);
            qfrag[s][kk] = *(bf16x8*)&q;
        }
    }

    float mrow[2] = {-1e30f, -1e30f};
    float lrow[2] = {0.0f, 0.0f};
    f32x4 oacc[2][4];
    #pragma unroll
    for (int s = 0; s < 2; ++s)
        #pragma unroll
        for (int dt = 0; dt < 4; ++dt) oacc[s][dt] = (f32x4){0.f, 0.f, 0.f, 0.f};

    const int dl = lane;
    const float* vcol = Vg + bh_base + dl;

    for (int kv0 = 0; kv0 < NS; kv0 += KVBLK) {
        #pragma unroll
        for (int i = 0; i < 4; ++i) {
            int cc = tid + i * 256;
            int row = cc >> 4, c4 = cc & 15;
            f32x4 f = *(const f32x4*)(Kg + bh_base + (long)(kv0 + row) * ND + c4 * 4);
            bf16v4 h;
            h[0] = (__bf16)f[0]; h[1] = (__bf16)f[1];
            h[2] = (__bf16)f[2]; h[3] = (__bf16)f[3];
            *(bf16v4*)(Kl + ((row * 128 + c4 * 8) ^ ((row & 7) << 4))) = h;
        }
        #pragma unroll
        for (int i = 0; i < 4; ++i) {
            int k0 = (wid + i * 4) * 4;
            float v0 = vcol[(long)(kv0 + k0 + 0) * ND];
            float v1 = vcol[(long)(kv0 + k0 + 1) * ND];
            float v2 = vcol[(long)(kv0 + k0 + 2) * ND];
            float v3 = vcol[(long)(kv0 + k0 + 3) * ND];
            bf16v4 h;
            h[0] = (__bf16)v0; h[1] = (__bf16)v1; h[2] = (__bf16)v2; h[3] = (__bf16)v3;
            *(bf16v4*)(Vl + dl * VSTRIDE_FB + k0 * 2) = h;
        }
        if (tid < KVBLK) {
            float mv = Mg[(long)b * NS + kv0 + tid];
            biasl[tid] = ((1.0f - mv) * NEG_MIN) * LOG2E;
        }
        __syncthreads();

        f32x4 st[2][4];
        #pragma unroll
        for (int t = 0; t < 4; ++t) {
            int key = t * 16 + c;
            int sw2 = (key & 7) << 4;
            bf16x8 kb0 = *(const bf16x8*)(Kl + ((key * 128 + g * 16) ^ sw2));
            bf16x8 kb1 = *(const bf16x8*)(Kl + ((key * 128 + 64 + g * 16) ^ sw2));
            f32x4 bias4 = *(const f32x4*)(biasl + t * 16 + g * 4);
            #pragma unroll
            for (int s = 0; s < 2; ++s) {
                f32x4 acc = (f32x4){0.f, 0.f, 0.f, 0.f};
                acc = __builtin_amdgcn_mfma_f32_16x16x32_bf16(kb0, qfrag[s][0], acc, 0, 0, 0);
                acc = __builtin_amdgcn_mfma_f32_16x16x32_bf16(kb1, qfrag[s][1], acc, 0, 0, 0);
                st[s][t] = acc + bias4;
            }
        }

        #pragma unroll
        for (int s = 0; s < 2; ++s) {
            float tm = st[s][0][0];
            #pragma unroll
            for (int t = 0; t < 4; ++t)
                #pragma unroll
                for (int r = 0; r < 4; ++r) tm = fmaxf(tm, st[s][t][r]);
            tm = fmaxf(tm, __shfl_xor(tm, 16));
            tm = fmaxf(tm, __shfl_xor(tm, 32));
            float mnew = fmaxf(mrow[s], tm);
            float scl = __builtin_amdgcn_exp2f(mrow[s] - mnew);
            mrow[s] = mnew;
            float ps = 0.f;
            #pragma unroll
            for (int t = 0; t < 4; ++t) {
                bf16v4 pb;
                #pragma unroll
                for (int r = 0; r < 4; ++r) {
                    float p = __builtin_amdgcn_exp2f(st[s][t][r] - mnew);
                    ps += p;
                    pb[r] = (__bf16)p;
                }
                *(bf16v4*)(Pw + (s * 16 + c) * PSTRIDE + (t * 16 + g * 4) * 2) = pb;
            }
            ps += __shfl_xor(ps, 16);
            ps += __shfl_xor(ps, 32);
            lrow[s] = lrow[s] * scl + ps;
            #pragma unroll
            for (int r = 0; r < 4; ++r) {
                float sb = __shfl(scl, g * 4 + r);
                #pragma unroll
                for (int dt = 0; dt < 4; ++dt) oacc[s][dt][r] *= sb;
            }
        }

        asm volatile("s_waitcnt lgkmcnt(0)" ::: "memory");
        __builtin_amdgcn_sched_barrier(0);

        bf16x8 pa[2][2];
        #pragma unroll
        for (int s = 0; s < 2; ++s)
            #pragma unroll
            for (int h = 0; h < 2; ++h)
                pa[s][h] = *(const bf16x8*)(Pw + (s * 16 + c) * PSTRIDE + h * 64 + g * 16);
        #pragma unroll
        for (int dt = 0; dt < 4; ++dt) {
            int d = dt * 16 + c;
            bf16x8 vb0 = *(const bf16x8*)(Vl + d * VSTRIDE_FB + g * 16);
            bf16x8 vb1 = *(const bf16x8*)(Vl + d * VSTRIDE_FB + 64 + g * 16);
            #pragma unroll
            for (int s = 0; s < 2; ++s) {
                oacc[s][dt] = __builtin_amdgcn_mfma_f32_16x16x32_bf16(pa[s][0], vb0, oacc[s][dt], 0, 0, 0);
                oacc[s][dt] = __builtin_amdgcn_mfma_f32_16x16x32_bf16(pa[s][1], vb1, oacc[s][dt], 0, 0, 0);
            }
        }
        __syncthreads();
    }

    #pragma unroll
    for (int s = 0; s < 2; ++s) {
        float inv = 1.0f / lrow[s];
        #pragma unroll
        for (int r = 0; r < 4; ++r) {
            float ib = __shfl(inv, g * 4 + r);
            float* op = Og + bh_base + (long)(qt * 128 + wid * 32 + s * 16 + g * 4 + r) * ND;
            #pragma unroll
            for (int dt = 0; dt < 4; ++dt)
                op[dt * 16 + c] = oacc[s][dt][r] * ib;
        }
    }
}

extern "C" void kernel_launch(void* const* d_in, const int* in_sizes, int n_in,
                              void* d_out, int out_size, void* d_ws, size_t ws_size,
                              hipStream_t stream) {
    const float* Q = (const float*)d_in[0];
    const float* K = (const float*)d_in[1];
    const float* V = (const float*)d_in[2];
    const float* M = (const float*)d_in[3];
    float* O = (float*)d_out;

    const size_t need = 2 * KWS_BYTES + (size_t)NB * NS * sizeof(float);
    if (ws_size >= need) {
        char*  Kws = (char*)d_ws;
        char*  Vws = Kws + KWS_BYTES;
        float* Bws = (float*)(Kws + 2 * KWS_BYTES);
        cvt_kv_kernel<<<dim3(32, 64), 256, 0, stream>>>(K, V, Kws, Vws);
        bias_kernel<<<dim3(NB * NS / 256), 256, 0, stream>>>(M, Bws);
        sdpa_fwd_kernel<<<dim3(8, 64), 512, 0, stream>>>(Q, Kws, Vws, Bws, O);
    } else {
        sdpa_fb_kernel<<<dim3(16, 64), 256, 0, stream>>>(Q, K, V, M, O);
    }
}